// Round 12
// baseline (34.718 us; speedup 1.0000x reference)
//
#include <hip/hip_runtime.h>
#include <hip/hip_bf16.h>

// AdaGuidedFilter: x:(4,64,256,256) f32 -> out same shape.
// out = x * (A*x + (1-A)*mean), A = var/(var+eps),
// mean/var from 11x11 zero-padded box sums normalized by in-window count.
//
// R11: barrier-free wave-local pipeline. Each wave owns an 8x64 output tile:
//  - vertical sliding sums for its 74 columns (64 + 10 halo via a second
//    short column pass on lanes 0..9) into a PRIVATE 5 KB LDS slice,
//    zero-padded at image edges (kills all column bounds checks in phase 2);
//  - sync = s_waitcnt lgkmcnt(0) only (no s_barrier, no vmcnt drain - the
//    xv prefetch stays in flight);
//  - horizontal sliding window + epilogue as in R6.
// LDS 4 x 5120 B = 20 KB/block -> 8 blocks/CU (32-wave cap). Swizzle
// (co&~7)|((co&7)^r), stride 80 qwords: same bank distribution R6 measured
// conflict-free for b64 writes and reads.

#define RAD    5
#define KW     11
#define IMG_H  256
#define IMG_W  256
#define TILE_H 8
#define IN_H   (TILE_H + 2 * RAD)   // 18
#define STRIPS (IMG_H / TILE_H)     // 32
#define NBLK   (256 * STRIPS)       // 8192
#define WSTR   80                   // float2 per LDS row (74 used)
#define EPS_F  0.01f

__device__ __forceinline__ int swz(int co, int r) {
    return (co & ~7) | ((co & 7) ^ r);
}

// vertical 11-row sliding sums for one column into the wave-local LDS slice
template<bool ROWCHECK>
__device__ __forceinline__ void colpass(const float* __restrict__ xim,
                                        float2* __restrict__ vb,
                                        int row0, int gc, bool colok, int co) {
    float xr[IN_H];
    #pragma unroll
    for (int li = 0; li < IN_H; ++li) {
        const int g = row0 + li;   // row check wave-uniform; col check per-lane
        const bool ok = colok && (!ROWCHECK || ((unsigned)g < (unsigned)IMG_H));
        xr[li] = ok ? xim[(size_t)g * IMG_W + gc] : 0.0f;
    }
    float s = 0.0f, s2 = 0.0f;
    #pragma unroll
    for (int li = 0; li < KW; ++li) { s += xr[li]; s2 = fmaf(xr[li], xr[li], s2); }
    #pragma unroll
    for (int r = 0; r < TILE_H; ++r) {
        vb[r * WSTR + swz(co, r)] = make_float2(s, s2);
        if (r < TILE_H - 1) {
            const float a = xr[r + KW], b = xr[r];
            s  += a - b;
            s2  = fmaf(a, a, fmaf(-b, b, s2));
        }
    }
}

template<bool ROWCHECK>
__device__ __forceinline__ void run_tile(const float* __restrict__ xim,
                                         float* __restrict__ oim,
                                         float2* __restrict__ vb,
                                         int strip, int C0, int l) {
    const int row0 = strip * TILE_H - RAD;

    // halo columns (local co 64..73 = global C0+59..C0+68), lanes 0..9
    if (l < 10) {
        const int gc = C0 + 59 + l;
        colpass<ROWCHECK>(xim, vb, row0, gc, gc < IMG_W, 64 + l);
    }
    // main columns (local co 0..63 = global C0-5..C0+58), all lanes
    {
        const int gc = C0 - 5 + l;
        colpass<ROWCHECK>(xim, vb, row0, gc, (unsigned)gc < (unsigned)IMG_W, l);
    }

    // phase-2 coords + epilogue-x prefetch (stays in flight across the wait)
    const int lr    = l & 7;
    const int seg   = l >> 3;          // 0..7, 8 output columns each
    const int gcol0 = C0 + seg * 8;
    const int gr    = strip * TILE_H + lr;

    float xv[8];
    {
        const float4* p = reinterpret_cast<const float4*>(xim + (size_t)gr * IMG_W + gcol0);
        const float4 q0 = p[0], q1 = p[1];
        xv[0]=q0.x; xv[1]=q0.y; xv[2]=q0.z; xv[3]=q0.w;
        xv[4]=q1.x; xv[5]=q1.y; xv[6]=q1.z; xv[7]=q1.w;
    }

    // wave-local sync: all our ds_writes complete before our ds_reads issue.
    asm volatile("s_waitcnt lgkmcnt(0)" ::: "memory");

    // ---- phase 2: horizontal sliding window + epilogue ----
    const int rlo = (gr - RAD < 0) ? 0 : gr - RAD;
    const int rhi = (gr + RAD > IMG_H - 1) ? IMG_H - 1 : gr + RAD;
    const float rcnt = (float)(rhi - rlo + 1);

    // window for px i covers local co = seg*8+i .. seg*8+i+10 (zero-padded,
    // no bounds checks); only the normalizer differs at image-edge columns.
    const int cob = seg * 8;
    float s = 0.0f, s2 = 0.0f;
    #pragma unroll
    for (int dd = 0; dd < KW; ++dd) {
        const float2 v = vb[lr * WSTR + swz(cob + dd, lr)];
        s += v.x; s2 += v.y;
    }

    float o[8];
    const bool edge = (C0 == 0 && seg == 0) || (C0 == 192 && seg == 7);
    if (!edge) {
        const float inv = __builtin_amdgcn_rcpf(rcnt * 11.0f);
        #pragma unroll
        for (int i = 0; i < 8; ++i) {
            const float mean = s * inv;
            const float m2   = s2 * inv;
            const float var  = fmaf(-mean, mean, m2);
            const float A    = var * __builtin_amdgcn_rcpf(var + EPS_F);
            const float xq   = xv[i];
            o[i] = xq * fmaf(A, xq - mean, mean);
            if (i < 7) {
                const float2 va = vb[lr * WSTR + swz(cob + i + KW, lr)];
                const float2 vs = vb[lr * WSTR + swz(cob + i, lr)];
                s  += va.x - vs.x;
                s2 += va.y - vs.y;
            }
        }
    } else {
        #pragma unroll
        for (int i = 0; i < 8; ++i) {
            const int c   = gcol0 + i;
            const int wlo = (c - RAD < 0) ? 0 : c - RAD;
            const int whi = (c + RAD > IMG_W - 1) ? IMG_W - 1 : c + RAD;
            const float inv  = __builtin_amdgcn_rcpf(rcnt * (float)(whi - wlo + 1));
            const float mean = s * inv;
            const float m2   = s2 * inv;
            const float var  = fmaf(-mean, mean, m2);
            const float A    = var * __builtin_amdgcn_rcpf(var + EPS_F);
            const float xq   = xv[i];
            o[i] = xq * fmaf(A, xq - mean, mean);
            if (i < 7) {
                const float2 va = vb[lr * WSTR + swz(cob + i + KW, lr)];
                const float2 vs = vb[lr * WSTR + swz(cob + i, lr)];
                s  += va.x - vs.x;
                s2 += va.y - vs.y;
            }
        }
    }

    float4* orow = reinterpret_cast<float4*>(oim + (size_t)gr * IMG_W + gcol0);
    orow[0] = make_float4(o[0], o[1], o[2], o[3]);
    orow[1] = make_float4(o[4], o[5], o[6], o[7]);
}

__global__ __launch_bounds__(256)
void AdaGuidedFilter_17686675325295_kernel(const float* __restrict__ x,
                                           float* __restrict__ out) {
    __shared__ float2 lds[4 * TILE_H * WSTR];   // 4 waves x 5120 B = 20480 B

    // XCD-chunked swizzle (8192 % 8 == 0 -> bijective)
    const int d     = blockIdx.x;
    const int L     = (d & 7) * (NBLK / 8) + (d >> 3);
    const int img   = L >> 5;            // 0..255
    const int strip = L & (STRIPS - 1);  // 0..31
    const int t     = threadIdx.x;
    const int wid   = t >> 6;            // wave 0..3 -> col-tile
    const int l     = t & 63;
    const int C0    = wid << 6;

    const float* __restrict__ xim = x   + (size_t)img * (IMG_H * IMG_W);
    float* __restrict__       oim = out + (size_t)img * (IMG_H * IMG_W);
    float2* __restrict__      vb  = lds + wid * (TILE_H * WSTR);

    if (strip != 0 && strip != STRIPS - 1)
        run_tile<false>(xim, oim, vb, strip, C0, l);
    else
        run_tile<true>(xim, oim, vb, strip, C0, l);
}

extern "C" void kernel_launch(void* const* d_in, const int* in_sizes, int n_in,
                              void* d_out, int out_size, void* d_ws, size_t ws_size,
                              hipStream_t stream) {
    (void)in_sizes; (void)n_in; (void)d_ws; (void)ws_size; (void)out_size;
    const float* x = (const float*)d_in[0];
    float* out = (float*)d_out;
    dim3 grid(NBLK);     // 8192 blocks
    dim3 block(256);
    AdaGuidedFilter_17686675325295_kernel<<<grid, block, 0, stream>>>(x, out);
}

// Round 13
// 34.294 us; speedup vs baseline: 1.0124x; 1.0124x over previous
//
#include <hip/hip_runtime.h>
#include <hip/hip_bf16.h>

// AdaGuidedFilter: x:(4,64,256,256) f32 -> out same shape.
// out = x * (A*x + (1-A)*mean), A = var/(var+eps),
// mean/var from 11x11 zero-padded box sums normalized by in-window count.
//
// R12: R6 body with TWO independent strips per block, fully interleaved:
// 36 row-loads in flight (2x memory parallelism), one barrier per 4096 px
// (vs R6's per-2048), zero redundant lanes, exact R6 LDS layout (c^r
// swizzle, 16 KB per strip, measured conflict-free). 32 KB LDS -> 5
// blocks/CU = 20 waves = R6's measured average residency.

#define RAD    5
#define KW     11
#define IMG_H  256
#define IMG_W  256
#define TILE_H 8
#define IN_H   (TILE_H + 2 * RAD)   // 18
#define PSTRIPS 16
#define NBLK   (256 * PSTRIPS)      // 4096
#define EPS_F  0.01f

__device__ __forceinline__ void phase2(const float2* __restrict__ vsum,
                                       float* __restrict__ oim,
                                       const float* xv,
                                       int lr, int seg, int c0, int gr) {
    const int rlo = (gr - RAD < 0) ? 0 : gr - RAD;
    const int rhi = (gr + RAD > IMG_H - 1) ? IMG_H - 1 : gr + RAD;
    const float rcnt = (float)(rhi - rlo + 1);

    float o[8];
    if (seg >= 1 && seg <= 30) {
        float s = 0.0f, s2 = 0.0f;
        #pragma unroll
        for (int dd = -RAD; dd <= RAD; ++dd) {
            const float2 v = vsum[(lr << 8) | ((c0 + dd) ^ lr)];
            s += v.x; s2 += v.y;
        }
        const float inv = __builtin_amdgcn_rcpf(rcnt * 11.0f);
        #pragma unroll
        for (int i = 0; i < 8; ++i) {
            const float mean = s * inv;
            const float m2   = s2 * inv;
            const float var  = fmaf(-mean, mean, m2);
            const float A    = var * __builtin_amdgcn_rcpf(var + EPS_F);
            const float xq   = xv[i];
            o[i] = xq * fmaf(A, xq - mean, mean);
            if (i < 7) {
                const float2 va = vsum[(lr << 8) | ((c0 + i + RAD + 1) ^ lr)];
                const float2 vb = vsum[(lr << 8) | ((c0 + i - RAD) ^ lr)];
                s  += va.x - vb.x;
                s2 += va.y - vb.y;
            }
        }
    } else {
        float s = 0.0f, s2 = 0.0f;
        #pragma unroll
        for (int dd = -RAD; dd <= RAD; ++dd) {
            const int cc = c0 + dd;
            if (cc >= 0 && cc < IMG_W) {
                const float2 v = vsum[(lr << 8) | (cc ^ lr)];
                s += v.x; s2 += v.y;
            }
        }
        #pragma unroll
        for (int i = 0; i < 8; ++i) {
            const int c   = c0 + i;
            const int wlo = (c - RAD < 0) ? 0 : c - RAD;
            const int whi = (c + RAD > IMG_W - 1) ? IMG_W - 1 : c + RAD;
            const float inv  = __builtin_amdgcn_rcpf(rcnt * (float)(whi - wlo + 1));
            const float mean = s * inv;
            const float m2   = s2 * inv;
            const float var  = fmaf(-mean, mean, m2);
            const float A    = var * __builtin_amdgcn_rcpf(var + EPS_F);
            const float xq   = xv[i];
            o[i] = xq * fmaf(A, xq - mean, mean);
            if (i < 7) {
                const int ca = c + RAD + 1;
                const int cs = c - RAD;
                if (ca < IMG_W) { const float2 v = vsum[(lr << 8) | (ca ^ lr)]; s += v.x; s2 += v.y; }
                if (cs >= 0)    { const float2 v = vsum[(lr << 8) | (cs ^ lr)]; s -= v.x; s2 -= v.y; }
            }
        }
    }

    float4* orow = reinterpret_cast<float4*>(oim + (size_t)gr * IMG_W + c0);
    orow[0] = make_float4(o[0], o[1], o[2], o[3]);
    orow[1] = make_float4(o[4], o[5], o[6], o[7]);
}

template<bool CHECKED>
__device__ __forceinline__ void run2(const float* __restrict__ xim,
                                     float* __restrict__ oim,
                                     float2* __restrict__ vsA,
                                     float2* __restrict__ vsB,
                                     int ps, int t) {
    const int sA = ps * 2, sB = ps * 2 + 1;
    const int row0A = sA * TILE_H - RAD;
    const int row0B = sB * TILE_H - RAD;

    // ---- phase 1: both strips, loads issued up-front (36 in flight) ----
    {
        float xrA[IN_H], xrB[IN_H];
        #pragma unroll
        for (int li = 0; li < IN_H; ++li) {
            const int gA = row0A + li;   // wave-uniform checks
            const int gB = row0B + li;
            xrA[li] = (!CHECKED || (unsigned)gA < (unsigned)IMG_H)
                        ? xim[(size_t)gA * IMG_W + t] : 0.0f;
            xrB[li] = (!CHECKED || (unsigned)gB < (unsigned)IMG_H)
                        ? xim[(size_t)gB * IMG_W + t] : 0.0f;
        }

        float a0 = 0.f, a2 = 0.f, b0 = 0.f, b2 = 0.f;
        #pragma unroll
        for (int li = 0; li < KW; ++li) {
            a0 += xrA[li]; a2 = fmaf(xrA[li], xrA[li], a2);
            b0 += xrB[li]; b2 = fmaf(xrB[li], xrB[li], b2);
        }
        #pragma unroll
        for (int r = 0; r < TILE_H; ++r) {
            vsA[(r << 8) | (t ^ r)] = make_float2(a0, a2);
            vsB[(r << 8) | (t ^ r)] = make_float2(b0, b2);
            if (r < TILE_H - 1) {
                float na = xrA[r + KW], oa = xrA[r];
                a0 += na - oa;  a2 = fmaf(na, na, fmaf(-oa, oa, a2));
                float nb = xrB[r + KW], ob = xrB[r];
                b0 += nb - ob;  b2 = fmaf(nb, nb, fmaf(-ob, ob, b2));
            }
        }
    }

    // xv prefetch for both strips (in flight across the barrier)
    const int lr  = t & 7;
    const int seg = t >> 3;
    const int c0  = seg * 8;
    const int grA = sA * TILE_H + lr;
    const int grB = sB * TILE_H + lr;

    float xvA[8], xvB[8];
    {
        const float4* pA = reinterpret_cast<const float4*>(xim + (size_t)grA * IMG_W + c0);
        const float4* pB = reinterpret_cast<const float4*>(xim + (size_t)grB * IMG_W + c0);
        const float4 a0 = pA[0], a1 = pA[1], b0 = pB[0], b1 = pB[1];
        xvA[0]=a0.x; xvA[1]=a0.y; xvA[2]=a0.z; xvA[3]=a0.w;
        xvA[4]=a1.x; xvA[5]=a1.y; xvA[6]=a1.z; xvA[7]=a1.w;
        xvB[0]=b0.x; xvB[1]=b0.y; xvB[2]=b0.z; xvB[3]=b0.w;
        xvB[4]=b1.x; xvB[5]=b1.y; xvB[6]=b1.z; xvB[7]=b1.w;
    }

    __syncthreads();

    // ---- phase 2: both strips ----
    phase2(vsA, oim, xvA, lr, seg, c0, grA);
    phase2(vsB, oim, xvB, lr, seg, c0, grB);
}

__global__ __launch_bounds__(256)
void AdaGuidedFilter_17686675325295_kernel(const float* __restrict__ x,
                                           float* __restrict__ out) {
    __shared__ float2 vsA[TILE_H * IMG_W];   // 16 KB
    __shared__ float2 vsB[TILE_H * IMG_W];   // 16 KB  (32 KB -> 5 blocks/CU)

    // XCD-chunked swizzle (4096 % 8 == 0 -> bijective)
    const int d   = blockIdx.x;
    const int L   = (d & 7) * (NBLK / 8) + (d >> 3);
    const int img = L >> 4;              // 0..255
    const int ps  = L & (PSTRIPS - 1);   // 0..15
    const int t   = threadIdx.x;

    const float* __restrict__ xim = x   + (size_t)img * (IMG_H * IMG_W);
    float* __restrict__       oim = out + (size_t)img * (IMG_H * IMG_W);

    if (ps != 0 && ps != PSTRIPS - 1)
        run2<false>(xim, oim, vsA, vsB, ps, t);
    else
        run2<true>(xim, oim, vsA, vsB, ps, t);
}

extern "C" void kernel_launch(void* const* d_in, const int* in_sizes, int n_in,
                              void* d_out, int out_size, void* d_ws, size_t ws_size,
                              hipStream_t stream) {
    (void)in_sizes; (void)n_in; (void)d_ws; (void)ws_size; (void)out_size;
    const float* x = (const float*)d_in[0];
    float* out = (float*)d_out;
    dim3 grid(NBLK);     // 4096 blocks
    dim3 block(256);
    AdaGuidedFilter_17686675325295_kernel<<<grid, block, 0, stream>>>(x, out);
}

// Round 14
// 30.843 us; speedup vs baseline: 1.1257x; 1.1119x over previous
//
#include <hip/hip_runtime.h>
#include <hip/hip_bf16.h>

// AdaGuidedFilter: x:(4,64,256,256) f32 -> out same shape.
// out = x * (A*x + (1-A)*mean), A = var/(var+eps),
// mean/var from 11x11 zero-padded box sums normalized by in-window count.
//
// R13: occupancy-max variant. TILE_H=4, 8 KB LDS -> wave-slot-capped
// (8 blocks = 32 waves/CU), far from the empirical 32KB-LDS residency cliff
// (R3/R9b/R12: ~half predicted occupancy at 32 KB; 16 KB fine). Costs 3.5x
// halo loads (L2/L3-absorbed, input is L3-resident). Same R6 one-barrier
// structure, c^r swizzle (same mod-16 residue distribution = conflict-free),
// 16384 short blocks for fine packing.

#define RAD    5
#define KW     11
#define IMG_H  256
#define IMG_W  256
#define TILE_H 4
#define IN_H   (TILE_H + 2 * RAD)   // 14
#define STRIPS (IMG_H / TILE_H)     // 64
#define NBLK   (256 * STRIPS)       // 16384
#define EPS_F  0.01f

template<bool ROWCHECK>
__device__ __forceinline__ void run_strip(const float* __restrict__ xim,
                                          float* __restrict__ oim,
                                          float2* __restrict__ vsum,
                                          int strip, int t) {
    const int row0 = strip * TILE_H - RAD;

    // ---- phase 1: vertical 11-row sliding sums, thread per column ----
    {
        float xr[IN_H];
        #pragma unroll
        for (int li = 0; li < IN_H; ++li) {
            const int g = row0 + li;   // wave-uniform check
            xr[li] = (!ROWCHECK || ((unsigned)g < (unsigned)IMG_H))
                       ? xim[(size_t)g * IMG_W + t] : 0.0f;
        }
        float s = 0.0f, s2 = 0.0f;
        #pragma unroll
        for (int li = 0; li < KW; ++li) { s += xr[li]; s2 = fmaf(xr[li], xr[li], s2); }
        #pragma unroll
        for (int r = 0; r < TILE_H; ++r) {
            vsum[(r << 8) | (t ^ r)] = make_float2(s, s2);
            if (r < TILE_H - 1) {
                const float a = xr[r + KW], b = xr[r];
                s  += a - b;
                s2  = fmaf(a, a, fmaf(-b, b, s2));
            }
        }
    }

    // phase-2 coords + xv prefetch (in flight across the barrier)
    const int lr  = t & 3;      // local row
    const int seg = t >> 2;     // 0..63, 4 columns each
    const int c0  = seg << 2;
    const int gr  = strip * TILE_H + lr;

    float xv[4];
    {
        const float4 q = *reinterpret_cast<const float4*>(xim + (size_t)gr * IMG_W + c0);
        xv[0] = q.x; xv[1] = q.y; xv[2] = q.z; xv[3] = q.w;
    }

    __syncthreads();

    // ---- phase 2: horizontal sliding window + epilogue ----
    const int rlo = (gr - RAD < 0) ? 0 : gr - RAD;
    const int rhi = (gr + RAD > IMG_H - 1) ? IMG_H - 1 : gr + RAD;
    const float rcnt = (float)(rhi - rlo + 1);

    float o[4];
    if (seg >= 2 && seg <= 61) {
        // interior: no column bounds, window width constant 11 -> one rcp
        float s = 0.0f, s2 = 0.0f;
        #pragma unroll
        for (int dd = -RAD; dd <= RAD; ++dd) {
            const float2 v = vsum[(lr << 8) | ((c0 + dd) ^ lr)];
            s += v.x; s2 += v.y;
        }
        const float inv = __builtin_amdgcn_rcpf(rcnt * 11.0f);
        #pragma unroll
        for (int i = 0; i < 4; ++i) {
            const float mean = s * inv;
            const float m2   = s2 * inv;
            const float var  = fmaf(-mean, mean, m2);
            const float A    = var * __builtin_amdgcn_rcpf(var + EPS_F);
            const float xq   = xv[i];
            o[i] = xq * fmaf(A, xq - mean, mean);
            if (i < 3) {
                const float2 va = vsum[(lr << 8) | ((c0 + i + RAD + 1) ^ lr)];
                const float2 vb = vsum[(lr << 8) | ((c0 + i - RAD) ^ lr)];
                s  += va.x - vb.x;
                s2 += va.y - vb.y;
            }
        }
    } else {
        // edge segments (0,1,62,63): bounds-checked sliding window
        float s = 0.0f, s2 = 0.0f;
        #pragma unroll
        for (int dd = -RAD; dd <= RAD; ++dd) {
            const int cc = c0 + dd;
            if (cc >= 0 && cc < IMG_W) {
                const float2 v = vsum[(lr << 8) | (cc ^ lr)];
                s += v.x; s2 += v.y;
            }
        }
        #pragma unroll
        for (int i = 0; i < 4; ++i) {
            const int c   = c0 + i;
            const int wlo = (c - RAD < 0) ? 0 : c - RAD;
            const int whi = (c + RAD > IMG_W - 1) ? IMG_W - 1 : c + RAD;
            const float inv  = __builtin_amdgcn_rcpf(rcnt * (float)(whi - wlo + 1));
            const float mean = s * inv;
            const float m2   = s2 * inv;
            const float var  = fmaf(-mean, mean, m2);
            const float A    = var * __builtin_amdgcn_rcpf(var + EPS_F);
            const float xq   = xv[i];
            o[i] = xq * fmaf(A, xq - mean, mean);
            if (i < 3) {
                const int ca = c + RAD + 1;
                const int cs = c - RAD;
                if (ca < IMG_W) { const float2 v = vsum[(lr << 8) | (ca ^ lr)]; s += v.x; s2 += v.y; }
                if (cs >= 0)    { const float2 v = vsum[(lr << 8) | (cs ^ lr)]; s -= v.x; s2 -= v.y; }
            }
        }
    }

    *reinterpret_cast<float4*>(oim + (size_t)gr * IMG_W + c0) =
        make_float4(o[0], o[1], o[2], o[3]);
}

__global__ __launch_bounds__(256)
void AdaGuidedFilter_17686675325295_kernel(const float* __restrict__ x,
                                           float* __restrict__ out) {
    __shared__ float2 vsum[TILE_H * IMG_W];   // 8192 B -> wave-slot-capped occupancy

    // XCD-chunked swizzle (16384 % 8 == 0 -> bijective): same image's strips
    // stay on one XCD -> halo rows L2-shared.
    const int d     = blockIdx.x;
    const int L     = (d & 7) * (NBLK / 8) + (d >> 3);
    const int img   = L >> 6;            // 0..255
    const int strip = L & (STRIPS - 1);  // 0..63
    const int t     = threadIdx.x;

    const float* __restrict__ xim = x   + (size_t)img * (IMG_H * IMG_W);
    float* __restrict__       oim = out + (size_t)img * (IMG_H * IMG_W);

    // rows go OOB when strip <= 1 (row0 < 0) or strip >= 62 (row0+13 > 255)
    if (strip >= 2 && strip <= STRIPS - 3)
        run_strip<false>(xim, oim, vsum, strip, t);
    else
        run_strip<true>(xim, oim, vsum, strip, t);
}

extern "C" void kernel_launch(void* const* d_in, const int* in_sizes, int n_in,
                              void* d_out, int out_size, void* d_ws, size_t ws_size,
                              hipStream_t stream) {
    (void)in_sizes; (void)n_in; (void)d_ws; (void)ws_size; (void)out_size;
    const float* x = (const float*)d_in[0];
    float* out = (float*)d_out;
    dim3 grid(NBLK);     // 16384 blocks
    dim3 block(256);
    AdaGuidedFilter_17686675325295_kernel<<<grid, block, 0, stream>>>(x, out);
}